// Round 5
// baseline (4770.871 us; speedup 1.0000x reference)
//
#include <hip/hip_runtime.h>
#include <cstdint>
#include <cstddef>

#define DD 128
#define ATS 68    // At row length: 64 rows + 4 pad
#define ARS 132   // gather-tile row stride (32 rows x 128 cols)
#define BQS 132   // B-quarter row stride (32 k x 128 cols)

// ---------------- CSR build (both graphs in one launch) ----------------

__global__ void count2_k(const int* __restrict__ dstb, const int* __restrict__ dstg,
                         int* __restrict__ degb, int* __restrict__ degg, int E, int gE) {
    int b = blockIdx.x;
    const int* dst = (b < gE) ? dstb : dstg;
    int* deg = (b < gE) ? degb : degg;
    int i = ((b < gE) ? b : b - gE) * blockDim.x + threadIdx.x;
    if (i < E) atomicAdd(&deg[dst[i]], 1);
}

__global__ __launch_bounds__(1024) void scan2_k(const int* __restrict__ degb,
                                                const int* __restrict__ degg,
                                                int* __restrict__ rpb, int* __restrict__ rpg,
                                                int* __restrict__ curb, int* __restrict__ curg,
                                                int n) {
    const int* deg = (blockIdx.x == 0) ? degb : degg;
    int* rp = (blockIdx.x == 0) ? rpb : rpg;
    int* cur = (blockIdx.x == 0) ? curb : curg;
    __shared__ int sums[1024];
    int tid = threadIdx.x;
    int per = (n + 1023) >> 10;
    int start = tid * per;
    int end = min(start + per, n);
    int s = 0;
    for (int i = start; i < end; ++i) s += deg[i];
    sums[tid] = s;
    __syncthreads();
    for (int off = 1; off < 1024; off <<= 1) {
        int v = (tid >= off) ? sums[tid - off] : 0;
        __syncthreads();
        sums[tid] += v;
        __syncthreads();
    }
    int pre = (tid == 0) ? 0 : sums[tid - 1];
    for (int i = start; i < end; ++i) {
        rp[i] = pre;
        cur[i] = pre;
        pre += deg[i];
    }
    if (end == n) rp[n] = pre;
}

__global__ void fill2_k(const int* __restrict__ srcb, const int* __restrict__ dstb,
                        const float* __restrict__ wb,
                        const int* __restrict__ srcg, const int* __restrict__ dstg,
                        const float* __restrict__ wg,
                        int* __restrict__ curb, int* __restrict__ curg,
                        int2* __restrict__ eb, int2* __restrict__ eg, int E, int gE) {
    int b = blockIdx.x;
    bool isb = (b < gE);
    const int* src = isb ? srcb : srcg;
    const int* dst = isb ? dstb : dstg;
    const float* w = isb ? wb : wg;
    int* cur = isb ? curb : curg;
    int2* edges = isb ? eb : eg;
    int i = (isb ? b : b - gE) * blockDim.x + threadIdx.x;
    if (i < E) {
        int d = dst[i];
        int pos = atomicAdd(&cur[d], 1);
        edges[pos] = make_int2(src[i], __float_as_int(w[i]));
    }
}

// ---------------- P = H H^T, S = H + H^T ----------------

__global__ __launch_bounds__(256) void prep_k(const float* __restrict__ H,
                                              float* __restrict__ P,
                                              float* __restrict__ S) {
    int idx = blockIdx.x * 256 + threadIdx.x;
    int i = idx >> 7, j = idx & 127;
    float acc = 0.f;
    for (int k = 0; k < DD; ++k) acc += H[i * DD + k] * H[j * DD + k];
    P[idx] = acc;
    S[idx] = H[i * DD + j] + H[j * DD + i];
}

// ---------------- Fused per-step kernel ----------------
// Block = 64 output rows x 128 cols, 256 threads.
// 1. gather Ab-tile (CSR) -> At^T ; GEMM S1 -> aS
// 2. gather Ag-tile        -> At^T ; GEMM S2 -> aS ; aS -= Ag
// 3. stage Y -> At^T ; GEMM P1 -> aP1 ; GEMM P2 -> aP2
// 4. epilogue: Yn = (2/3)Y + (1/3)(aS - db*aP1 - dg*aP2 + X + dg*Y)/(db+dg+1)
// LDS: At 34816 B + U 16896 B = 51712 -> 3 blocks/CU (3 waves/SIMD).

__global__ __launch_bounds__(256, 3) void step_k(
    const float* __restrict__ Yc, const float* __restrict__ X,
    const int* __restrict__ rpb, const int2* __restrict__ eb,
    const int* __restrict__ rpg, const int2* __restrict__ eg,
    const float* __restrict__ db, const float* __restrict__ dg,
    const float* __restrict__ P1, const float* __restrict__ P2,
    const float* __restrict__ S1, const float* __restrict__ S2,
    float* __restrict__ Yn, int n)
{
    __shared__ float At[DD * ATS];
    __shared__ float U[32 * ARS];   // union: gather half-tile (row-major) / B quarter

    const int tid = threadIdx.x;
    const int lane = tid & 63;
    const int wv = tid >> 6;        // wave 0..3
    const int cg = tid & 15;        // col group: cols {cg*4..+3} and {64+cg*4..+3}
    const int rg = tid >> 4;        // row group 0..15: rows rg*4..+3
    const int row0 = blockIdx.x * 64;

    float aS[4][8], aP1[4][8], aP2[4][8];
#pragma unroll
    for (int i = 0; i < 4; ++i)
#pragma unroll
        for (int j = 0; j < 8; ++j) { aS[i][j] = 0.f; aP1[i][j] = 0.f; aP2[i][j] = 0.f; }

    // ---- gather one graph's tile into At (transposed): At[c][r] = (A@Y)[row0+r][c]
    auto gatherA = [&](const int* __restrict__ rp, const int2* __restrict__ edges) {
        for (int h = 0; h < 2; ++h) {
#pragma unroll 1
            for (int it = 0; it < 8; ++it) {
                int r = wv * 8 + it;            // local row within half (0..31)
                int node = row0 + h * 32 + r;
                float a0 = 0.f, a1 = 0.f;
                if (node < n) {
                    int beg = rp[node], end = rp[node + 1];
                    int j = beg;
                    for (; j + 4 <= end; j += 4) {
                        int2 e0 = edges[j + 0], e1 = edges[j + 1];
                        int2 e2 = edges[j + 2], e3 = edges[j + 3];
                        float2 f0 = *((const float2*)(Yc + (size_t)e0.x * DD) + lane);
                        float2 f1 = *((const float2*)(Yc + (size_t)e1.x * DD) + lane);
                        float2 f2 = *((const float2*)(Yc + (size_t)e2.x * DD) + lane);
                        float2 f3 = *((const float2*)(Yc + (size_t)e3.x * DD) + lane);
                        float w0 = __int_as_float(e0.y), w1 = __int_as_float(e1.y);
                        float w2 = __int_as_float(e2.y), w3 = __int_as_float(e3.y);
                        a0 += w0 * f0.x; a1 += w0 * f0.y;
                        a0 += w1 * f1.x; a1 += w1 * f1.y;
                        a0 += w2 * f2.x; a1 += w2 * f2.y;
                        a0 += w3 * f3.x; a1 += w3 * f3.y;
                    }
                    for (; j < end; ++j) {
                        int2 e = edges[j];
                        float2 f = *((const float2*)(Yc + (size_t)e.x * DD) + lane);
                        float wv2 = __int_as_float(e.y);
                        a0 += wv2 * f.x; a1 += wv2 * f.y;
                    }
                }
                *reinterpret_cast<float2*>(&U[r * ARS + 2 * lane]) = make_float2(a0, a1);
            }
            __syncthreads();
            // transpose U[32][128] -> At[*][h*32 + r]
            {
                int r = tid & 31;
                int cb = (tid >> 5) * 16;
#pragma unroll
                for (int u = 0; u < 4; ++u) {
                    float4 v = *reinterpret_cast<const float4*>(&U[r * ARS + cb + 4 * u]);
                    int c = cb + 4 * u;
                    At[(c + 0) * ATS + h * 32 + r] = v.x;
                    At[(c + 1) * ATS + h * 32 + r] = v.y;
                    At[(c + 2) * ATS + h * 32 + r] = v.z;
                    At[(c + 3) * ATS + h * 32 + r] = v.w;
                }
            }
            __syncthreads();
        }
    };

    // ---- stage Y tile from global into At (transposed) ----
    auto stageY = [&]() {
        int r = tid >> 2;
        int rowc = min(row0 + r, n - 1);
        const float* gp = Yc + (size_t)rowc * DD;
#pragma unroll
        for (int i = 0; i < 8; ++i) {
            int c = ((tid & 3) << 2) + (i << 4);
            float4 v = *reinterpret_cast<const float4*>(gp + c);
            At[(c + 0) * ATS + r] = v.x;
            At[(c + 1) * ATS + r] = v.y;
            At[(c + 2) * ATS + r] = v.z;
            At[(c + 3) * ATS + r] = v.w;
        }
    };

    // ---- GEMM: acc += Atile @ M, quarter-K staged B in U ----
    auto gemm = [&](const float* __restrict__ M, float (&acc)[4][8]) {
#pragma unroll 1
        for (int kq = 0; kq < 4; ++kq) {
            {   // stage B quarter: U[kl][c] = M[kq*32+kl][c]
                int kl = tid & 31;
                int cb = (tid >> 5) * 16;
                const float* gp = M + (size_t)(kq * 32 + kl) * DD + cb;
                float* bp = U + kl * BQS + cb;
#pragma unroll
                for (int u = 0; u < 4; ++u)
                    *reinterpret_cast<float4*>(bp + 4 * u) =
                        *reinterpret_cast<const float4*>(gp + 4 * u);
            }
            __syncthreads();
#pragma unroll 2
            for (int kl = 0; kl < 32; ++kl) {
                int k = kq * 32 + kl;
                float4 a = *reinterpret_cast<const float4*>(&At[k * ATS + rg * 4]);
                float4 b0 = *reinterpret_cast<const float4*>(&U[kl * BQS + cg * 4]);
                float4 b1 = *reinterpret_cast<const float4*>(&U[kl * BQS + 64 + cg * 4]);
                float av[4] = {a.x, a.y, a.z, a.w};
                float bv[8] = {b0.x, b0.y, b0.z, b0.w, b1.x, b1.y, b1.z, b1.w};
#pragma unroll
                for (int i = 0; i < 4; ++i)
#pragma unroll
                    for (int j = 0; j < 8; ++j) acc[i][j] += av[i] * bv[j];
            }
            __syncthreads();
        }
    };

    // ---- 1: Ab tile, S1 ----
    gatherA(rpb, eb);
    gemm(S1, aS);

    // ---- 2: Ag tile, S2, fold -Ag ----
    gatherA(rpg, eg);
    gemm(S2, aS);
#pragma unroll
    for (int i = 0; i < 4; ++i) {
        int r = rg * 4 + i;
#pragma unroll
        for (int j = 0; j < 8; ++j) {
            int c = (j >> 2) * 64 + cg * 4 + (j & 3);
            aS[i][j] -= At[c * ATS + r];
        }
    }
    __syncthreads();

    // ---- 3: Y tile, P1, P2 ----
    stageY();
    __syncthreads();
    gemm(P1, aP1);
    gemm(P2, aP2);

    // ---- 4: epilogue ----
    const float AL = 1.0f / 3.0f;
#pragma unroll
    for (int i = 0; i < 4; ++i) {
        int row = row0 + rg * 4 + i;
        if (row < n) {
            float dbv = db[row], dgv = dg[row];
            float aq = AL / (dbv + dgv + 1.0f);
#pragma unroll
            for (int hh = 0; hh < 2; ++hh) {
                size_t off = (size_t)row * DD + hh * 64 + cg * 4;
                float4 y = *reinterpret_cast<const float4*>(Yc + off);
                float4 x = *reinterpret_cast<const float4*>(X + off);
                float yv[4] = {y.x, y.y, y.z, y.w};
                float xv[4] = {x.x, x.y, x.z, x.w};
                float ov[4];
#pragma unroll
                for (int q = 0; q < 4; ++q) {
                    int j = hh * 4 + q;
                    float yhat = aS[i][j] - dbv * aP1[i][j] - dgv * aP2[i][j]
                                 + xv[q] + dgv * yv[q];
                    ov[q] = (1.0f - AL) * yv[q] + yhat * aq;
                }
                *reinterpret_cast<float4*>(Yn + off) = make_float4(ov[0], ov[1], ov[2], ov[3]);
            }
        }
    }
}

// ---------------- host ----------------

extern "C" void kernel_launch(void* const* d_in, const int* in_sizes, int n_in,
                              void* d_out, int out_size, void* d_ws, size_t ws_size,
                              hipStream_t stream) {
    const float* X   = (const float*)d_in[0];
    const float* H1  = (const float*)d_in[1];
    const float* H2  = (const float*)d_in[2];
    const float* wb  = (const float*)d_in[3];
    const float* wg  = (const float*)d_in[4];
    const float* db  = (const float*)d_in[5];
    const float* dg  = (const float*)d_in[6];
    const int* srcb  = (const int*)d_in[7];
    const int* dstb  = (const int*)d_in[8];
    const int* srcg  = (const int*)d_in[9];
    const int* dstg  = (const int*)d_in[10];
    const int N = in_sizes[5];
    const int E = in_sizes[3];
    float* Yout = (float*)d_out;

    char* p = (char*)d_ws;
    auto alloc = [&](size_t b) -> void* {
        void* r = (void*)p;
        p += (b + 255) & ~(size_t)255;
        return r;
    };
    float* P1 = (float*)alloc((size_t)DD * DD * 4);
    float* S1 = (float*)alloc((size_t)DD * DD * 4);
    float* P2 = (float*)alloc((size_t)DD * DD * 4);
    float* S2 = (float*)alloc((size_t)DD * DD * 4);
    int* degb = (int*)alloc((size_t)N * 4);
    int* degg = (int*)alloc((size_t)N * 4);
    int* rpb  = (int*)alloc((size_t)(N + 1) * 4);
    int* rpg  = (int*)alloc((size_t)(N + 1) * 4);
    int* curb = (int*)alloc((size_t)N * 4);
    int* curg = (int*)alloc((size_t)N * 4);
    int2* eb  = (int2*)alloc((size_t)E * 8);
    int2* eg  = (int2*)alloc((size_t)E * 8);
    float* Yw  = (float*)alloc((size_t)N * DD * 4);

    hipMemsetAsync(degb, 0, (size_t)N * 4, stream);
    hipMemsetAsync(degg, 0, (size_t)N * 4, stream);

    int gE = (E + 255) / 256;
    count2_k<<<2 * gE, 256, 0, stream>>>(dstb, dstg, degb, degg, E, gE);
    scan2_k<<<2, 1024, 0, stream>>>(degb, degg, rpb, rpg, curb, curg, N);
    fill2_k<<<2 * gE, 256, 0, stream>>>(srcb, dstb, wb, srcg, dstg, wg,
                                        curb, curg, eb, eg, E, gE);
    prep_k<<<64, 256, 0, stream>>>(H1, P1, S1);
    prep_k<<<64, 256, 0, stream>>>(H2, P2, S2);

    const float* Ycur = X;
    float* Ybufs[2] = {Yw, Yout};
    int gd = (N + 63) / 64;
    for (int s = 0; s < 8; ++s) {
        float* Yn = Ybufs[s & 1];
        step_k<<<gd, 256, 0, stream>>>(Ycur, X, rpb, eb, rpg, eg, db, dg,
                                       P1, P2, S1, S2, Yn, N);
        Ycur = Yn;
    }
}